// Round 8
// baseline (326.747 us; speedup 1.0000x reference)
//
#include <hip/hip_runtime.h>
#include <stdint.h>

typedef __bf16 bf16;
typedef bf16 bf16x8 __attribute__((ext_vector_type(8)));
typedef bf16 bf16x4 __attribute__((ext_vector_type(4)));
typedef float f32x4 __attribute__((ext_vector_type(4)));

constexpr int B_ = 2, L_ = 2048, D_ = 1024, H_ = 16, DH_ = 64;
constexpr int M_ = B_ * L_;                     // 4096
constexpr float QSCALE = 0.125f * 1.44269504f;  // softmax scale * log2(e), folded into Q

__device__ __forceinline__ void gload_lds16(const void* g, void* l) {
  __builtin_amdgcn_global_load_lds(
      (const __attribute__((address_space(1))) unsigned int*)g,
      (__attribute__((address_space(3))) unsigned int*)l, 16, 0, 0);
}
#define MEMBAR() asm volatile("" ::: "memory")
__device__ __forceinline__ void block_bar() {
  MEMBAR(); __builtin_amdgcn_s_barrier(); MEMBAR();
}

// ---------------- fused cast fp32 -> bf16 for q,k,v (round-3 proven) ----------------
__global__ void cast3(const float* __restrict__ q, const float* __restrict__ k,
                      const float* __restrict__ v, bf16* __restrict__ dst) {
  const float* src = blockIdx.y == 0 ? q : (blockIdx.y == 1 ? k : v);
  size_t i = (size_t)blockIdx.x * blockDim.x + threadIdx.x;
  float4 val = reinterpret_cast<const float4*>(src)[i];
  bf16x4 o;
  o[0] = (bf16)val.x; o[1] = (bf16)val.y; o[2] = (bf16)val.z; o[3] = (bf16)val.w;
  reinterpret_cast<bf16x4*>(dst + (size_t)blockIdx.y * M_ * D_)[i] = o;
}

// ---------------- batched weight transpose+cast: W[K][N] -> WT[z][N][K] ----------------
__global__ void transpose_cast_w(const float* __restrict__ W0, const float* __restrict__ W1,
                                 const float* __restrict__ W2, const float* __restrict__ W3,
                                 bf16* __restrict__ WT) {
  __shared__ float tile[32][33];
  const float* W = blockIdx.z == 0 ? W0 : blockIdx.z == 1 ? W1 : blockIdx.z == 2 ? W2 : W3;
  bf16* Wt = WT + (size_t)blockIdx.z * D_ * D_;
  int tx = threadIdx.x, ty = threadIdx.y;  // 32 x 8
  int r0 = blockIdx.y * 32, c0 = blockIdx.x * 32;
#pragma unroll
  for (int i = 0; i < 32; i += 8)
    tile[ty + i][tx] = W[(size_t)(r0 + ty + i) * D_ + c0 + tx];
  __syncthreads();
#pragma unroll
  for (int i = 0; i < 32; i += 8)
    Wt[(size_t)(c0 + ty + i) * D_ + r0 + tx] = (bf16)tile[tx][ty + i];
}

// ---------------- GEMM (round-1/3 proven): C = A * Bt^T + bias, BK=64 dbuf ----------------
// MODE 0: bf16 -> [B,H,L,DH] (*oscale)   MODE 1: bf16 -> [B,H,DH,L]   MODE 2: fp32 [M][N]
constexpr int BM = 128, BN = 64, BK = 64;

template <int MODE>
__global__ __launch_bounds__(256) void gemm_bf16(
    const bf16* __restrict__ A, const bf16* __restrict__ Bt,
    const float* __restrict__ bias, void* __restrict__ outp, float oscale) {
  __shared__ bf16 As[2][BM * BK];   // 16KB each, XOR-swizzled rows (128B)
  __shared__ bf16 Bs[2][BN * BK];   // 8KB each
  const int tid = threadIdx.x;
  const int wid = tid >> 6, lane = tid & 63;
  const int lr = lane & 15, lg = lane >> 4;
  const int wr = wid >> 1, wc = wid & 1;  // 2x2 waves, wave tile 64x32

  // XCD-bijective block swizzle (nwg = 512, divisible by 8)
  const int bidf = blockIdx.y * gridDim.x + blockIdx.x;
  const int cpx = (gridDim.x * gridDim.y) >> 3;
  const int swz = (bidf & 7) * cpx + (bidf >> 3);
  const int n0 = (swz % gridDim.x) * BN, m0 = (swz / gridDim.x) * BM;

  f32x4 acc[4][2] = {};

  auto stage = [&](int bsel, int kt) {
#pragma unroll
    for (int i = 0; i < 4; ++i) {           // A: 16 x 1KB slots
      int slot = i * 4 + wid;
      int c = slot * 64 + lane;             // chunk 0..1023; row = c>>3, 8 chunks/row
      int row = c >> 3, cs = c & 7, g = cs ^ (row & 7);
      gload_lds16(A + (size_t)(m0 + row) * D_ + kt + g * 8, (char*)As[bsel] + slot * 1024);
    }
#pragma unroll
    for (int i = 0; i < 2; ++i) {           // B: 8 x 1KB slots
      int slot = i * 4 + wid;
      int c = slot * 64 + lane;
      int row = c >> 3, cs = c & 7, g = cs ^ (row & 7);
      gload_lds16(Bt + (size_t)(n0 + row) * D_ + kt + g * 8, (char*)Bs[bsel] + slot * 1024);
    }
  };

  stage(0, 0);
  for (int t = 0; t < D_ / BK; ++t) {
    const int cur = t & 1;
    if (t < D_ / BK - 1) {
      stage(cur ^ 1, (t + 1) * BK);
      asm volatile("s_waitcnt vmcnt(6)" ::: "memory");   // only cur's 6 must be done
    } else {
      asm volatile("s_waitcnt vmcnt(0)" ::: "memory");
    }
    block_bar();
#pragma unroll
    for (int kk = 0; kk < 2; ++kk) {
      bf16x8 af[4], bfr[2];
#pragma unroll
      for (int i = 0; i < 4; ++i) {
        int R = wr * 64 + i * 16 + lr;
        int ch = (kk * 4 + lg) ^ (R & 7);
        af[i] = *(const bf16x8*)((char*)As[cur] + R * 128 + ch * 16);
      }
#pragma unroll
      for (int j = 0; j < 2; ++j) {
        int R = wc * 32 + j * 16 + lr;
        int ch = (kk * 4 + lg) ^ (R & 7);
        bfr[j] = *(const bf16x8*)((char*)Bs[cur] + R * 128 + ch * 16);
      }
#pragma unroll
      for (int i = 0; i < 4; ++i)
#pragma unroll
        for (int j = 0; j < 2; ++j)
          acc[i][j] = __builtin_amdgcn_mfma_f32_16x16x32_bf16(af[i], bfr[j], acc[i][j], 0, 0, 0);
    }
    block_bar();
  }

  // epilogue: C/D layout col = lane&15, row = (lane>>4)*4 + r
#pragma unroll
  for (int i = 0; i < 4; ++i) {
#pragma unroll
    for (int j = 0; j < 2; ++j) {
      const int n = n0 + wc * 32 + j * 16 + lr;
      const float bn = bias[n];
      const int mbase = m0 + wr * 64 + i * 16 + lg * 4;
      if constexpr (MODE == 2) {
        float* out = (float*)outp;
#pragma unroll
        for (int r = 0; r < 4; ++r)
          out[(size_t)(mbase + r) * D_ + n] = acc[i][j][r] + bn;
      } else if constexpr (MODE == 0) {
        bf16* out = (bf16*)outp;
        const int h = n >> 6, dh = n & 63;
#pragma unroll
        for (int r = 0; r < 4; ++r) {
          int m = mbase + r;
          int b = m >> 11, l = m & (L_ - 1);
          out[((size_t)(b * H_ + h) * L_ + l) * DH_ + dh] = (bf16)((acc[i][j][r] + bn) * oscale);
        }
      } else {  // MODE 1: Vt[b][h][dh][l]
        bf16* out = (bf16*)outp;
        const int h = n >> 6, dh = n & 63;
        int b = mbase >> 11, l = mbase & (L_ - 1);
        bf16x4 pk;
#pragma unroll
        for (int r = 0; r < 4; ++r) pk[r] = (bf16)(acc[i][j][r] + bn);
        *(bf16x4*)(out + ((size_t)(b * H_ + h) * DH_ + dh) * L_ + l) = pk;
      }
    }
  }
}

// ---------------- flash attention: ROUND-3-EXACT structure, direct-global K/V only ------
// grid (32, H, B), block 128 (2 waves). Block x handles 32-row q-tiles {x, 63-x}.
// ONLY change vs the round-3 passing kernel: K/V staged-LDS reads replaced by direct
// global reads (provably value-identical); staging + vmcnt deleted. Barriers, decode,
// launch_bounds, block-level ktmax, monolithic smx_pv all kept verbatim.
__global__ __launch_bounds__(128, 2) void attn_fwd(
    const bf16* __restrict__ Q,   // [B,H,L,DH], pre-scaled by QSCALE
    const bf16* __restrict__ K,   // [B,H,L,DH]
    const bf16* __restrict__ Vt,  // [B,H,DH,L]
    bf16* __restrict__ O) {       // [B,L,D]
  __shared__ bf16 Ps[2][16 * 72];   // per-wave P strip (shared by both q-tiles)
  const int tid = threadIdx.x;
  const int wid = tid >> 6, lane = tid & 63;
  const int lr = lane & 15, lg = lane >> 4;
  const int x = blockIdx.x;
  const int h = blockIdx.y, b = blockIdx.z;
  const size_t bh = (size_t)b * H_ + h;
  const int qtA = x, qtB = 63 - x;
  const int qr0A = qtA * 32 + wid * 16, qr0B = qtB * 32 + wid * 16;
  const int ktmaxA = (qtA * 32 + 31) >> 6, ktmaxB = (qtB * 32 + 31) >> 6;

  bf16x8 qfA[2], qfB[2];
  {
    const bf16* qa = Q + (bh * L_ + qr0A) * DH_;
    const bf16* qb = Q + (bh * L_ + qr0B) * DH_;
#pragma unroll
    for (int kk = 0; kk < 2; ++kk) {
      qfA[kk] = *(const bf16x8*)(qa + lr * DH_ + kk * 32 + lg * 8);
      qfB[kk] = *(const bf16x8*)(qb + lr * DH_ + kk * 32 + lg * 8);
    }
  }

  f32x4 oA[4] = {}, oB[4] = {};
  float mA[4], lA[4], mB[4], lB[4];
#pragma unroll
  for (int r = 0; r < 4; ++r) { mA[r] = mB[r] = -3.0e38f; lA[r] = lB[r] = 0.f; }

  bf16* pw = &Ps[wid][0];

  auto smx_pv = [&](f32x4* s, float* m, float* l, f32x4* o, const bf16* vb) {
    float t4[4];
#pragma unroll
    for (int r = 0; r < 4; ++r)
      t4[r] = fmaxf(fmaxf(s[0][r], s[1][r]), fmaxf(s[2][r], s[3][r]));
#pragma unroll
    for (int d = 1; d < 16; d <<= 1)
#pragma unroll
      for (int r = 0; r < 4; ++r) t4[r] = fmaxf(t4[r], __shfl_xor(t4[r], d));
    bool need = false;
#pragma unroll
    for (int r = 0; r < 4; ++r) need |= (t4[r] > m[r] + 11.0f);
    if (__any(need)) {  // defer-max
#pragma unroll
      for (int r = 0; r < 4; ++r) {
        float mn = fmaxf(m[r], t4[r]);
        float c = exp2f(m[r] - mn);
        m[r] = mn; l[r] *= c;
#pragma unroll
        for (int j = 0; j < 4; ++j) o[j][r] *= c;
      }
    }
    float rs[4] = {0.f, 0.f, 0.f, 0.f};
#pragma unroll
    for (int j = 0; j < 4; ++j)
#pragma unroll
      for (int r = 0; r < 4; ++r) {
        float p = exp2f(s[j][r] - m[r]);
        s[j][r] = p;
        rs[r] += p;
      }
#pragma unroll
    for (int d = 1; d < 16; d <<= 1)
#pragma unroll
      for (int r = 0; r < 4; ++r) rs[r] += __shfl_xor(rs[r], d);
#pragma unroll
    for (int r = 0; r < 4; ++r) l[r] += rs[r];
    // P bounce through padded LDS strip (stride 72 el)
#pragma unroll
    for (int j = 0; j < 4; ++j)
#pragma unroll
      for (int r = 0; r < 4; ++r)
        pw[(lg * 4 + r) * 72 + j * 16 + lr] = (bf16)s[j][r];
    bf16x8 ap[2];
#pragma unroll
    for (int st = 0; st < 2; ++st)
      ap[st] = *(const bf16x8*)(pw + lr * 72 + st * 32 + lg * 8);
#pragma unroll
    for (int j = 0; j < 4; ++j) {
      const bf16* vr = vb + (size_t)(j * 16 + lr) * L_ + lg * 8;
      bf16x8 v0 = *(const bf16x8*)vr;
      bf16x8 v1 = *(const bf16x8*)(vr + 32);
      o[j] = __builtin_amdgcn_mfma_f32_16x16x32_bf16(ap[0], v0, o[j], 0, 0, 0);
      o[j] = __builtin_amdgcn_mfma_f32_16x16x32_bf16(ap[1], v1, o[j], 0, 0, 0);
    }
  };

  for (int kt = 0; kt <= ktmaxB; ++kt) {
    block_bar();
    const bool actA = (kt <= ktmaxA);
    const bf16* kb = K + (bh * L_ + (size_t)kt * 64) * DH_;
    const bf16* vb = Vt + bh * (size_t)DH_ * L_ + (size_t)kt * 64;

    f32x4 sA[4] = {}, sB[4] = {};
#pragma unroll
    for (int j = 0; j < 4; ++j) {  // K fragments shared by both strips
      const bf16* kr = kb + (size_t)(j * 16 + lr) * DH_ + lg * 8;
      bf16x8 k0 = *(const bf16x8*)kr;
      bf16x8 k1 = *(const bf16x8*)(kr + 32);
      sB[j] = __builtin_amdgcn_mfma_f32_16x16x32_bf16(qfB[0], k0, sB[j], 0, 0, 0);
      sB[j] = __builtin_amdgcn_mfma_f32_16x16x32_bf16(qfB[1], k1, sB[j], 0, 0, 0);
      if (actA) {
        sA[j] = __builtin_amdgcn_mfma_f32_16x16x32_bf16(qfA[0], k0, sA[j], 0, 0, 0);
        sA[j] = __builtin_amdgcn_mfma_f32_16x16x32_bf16(qfA[1], k1, sA[j], 0, 0, 0);
      }
    }

    if (kt == ktmaxB) {
#pragma unroll
      for (int j = 0; j < 4; ++j) {
        int key = kt * 64 + j * 16 + lr;
#pragma unroll
        for (int r = 0; r < 4; ++r)
          if (key > qr0B + lg * 4 + r) sB[j][r] = -1.0e30f;
      }
    }
    smx_pv(sB, mB, lB, oB, vb);
    if (actA) {
      if (kt == ktmaxA) {
#pragma unroll
        for (int j = 0; j < 4; ++j) {
          int key = kt * 64 + j * 16 + lr;
#pragma unroll
          for (int r = 0; r < 4; ++r)
            if (key > qr0A + lg * 4 + r) sA[j][r] = -1.0e30f;
        }
      }
      smx_pv(sA, mA, lA, oA, vb);
    }
    block_bar();
  }

  // epilogue
#pragma unroll
  for (int j = 0; j < 4; ++j)
#pragma unroll
    for (int r = 0; r < 4; ++r) {
      int dh = j * 16 + lr;
      O[((size_t)b * L_ + qr0A + lg * 4 + r) * D_ + h * DH_ + dh] = (bf16)(oA[j][r] / lA[r]);
      O[((size_t)b * L_ + qr0B + lg * 4 + r) * D_ + h * DH_ + dh] = (bf16)(oB[j][r] / lB[r]);
    }
}

// ---------------- launcher (round-3 proven structure) ----------------
extern "C" void kernel_launch(void* const* d_in, const int* in_sizes, int n_in,
                              void* d_out, int out_size, void* d_ws, size_t ws_size,
                              hipStream_t stream) {
  const float* q  = (const float*)d_in[0];
  const float* k  = (const float*)d_in[1];
  const float* v  = (const float*)d_in[2];
  const float* Wq = (const float*)d_in[4];
  const float* bq = (const float*)d_in[5];
  const float* Wk = (const float*)d_in[6];
  const float* bk = (const float*)d_in[7];
  const float* Wv = (const float*)d_in[8];
  const float* bv = (const float*)d_in[9];
  const float* Wo = (const float*)d_in[10];
  const float* bo = (const float*)d_in[11];

  // ws layout (40MB): castQ[0,8) castK[8,16) castV[16,24) WT[24,32) Vtb[32,40)
  char* ws = (char*)d_ws;
  bf16* castQ = (bf16*)ws;
  bf16* castK = (bf16*)(ws + (8ull << 20));
  bf16* castV = (bf16*)(ws + (16ull << 20));
  bf16* WT    = (bf16*)(ws + (24ull << 20));
  bf16* Vtb   = (bf16*)(ws + (32ull << 20));
  bf16* Kb    = (bf16*)(ws + (16ull << 20));  // over castV (dead after V-GEMM)
  bf16* Qb    = (bf16*)(ws + (8ull << 20));   // over castK (dead after K-GEMM)
  bf16* Ob    = (bf16*)ws;                    // over castQ (dead after Q-GEMM)

  transpose_cast_w<<<dim3(32, 32, 4), dim3(32, 8), 0, stream>>>(Wq, Wk, Wv, Wo, WT);
  cast3<<<dim3((M_ * D_ / 4) / 256, 3), 256, 0, stream>>>(q, k, v, castQ);

  dim3 gg(D_ / BN, M_ / BM);  // (16, 32) = 512 blocks
  gemm_bf16<1><<<gg, 256, 0, stream>>>(castV, WT + 2ull * D_ * D_, bv, Vtb, 1.0f);
  gemm_bf16<0><<<gg, 256, 0, stream>>>(castK, WT + 1ull * D_ * D_, bk, Kb, 1.0f);
  gemm_bf16<0><<<gg, 256, 0, stream>>>(castQ, WT, bq, Qb, QSCALE);

  attn_fwd<<<dim3(32, H_, B_), 128, 0, stream>>>(Qb, Kb, Vtb, Ob);

  gemm_bf16<2><<<gg, 256, 0, stream>>>(Ob, WT + 3ull * D_ * D_, bo, (float*)d_out, 1.0f);
}